// Round 7
// baseline (573.034 us; speedup 1.0000x reference)
//
#include <hip/hip_runtime.h>

// WindowAttention: B=256 windows, N=256 tokens, C=384, 12 heads, d=32.
// Pipeline: K0 cast weights->bf16 | K1 transpose-cast x -> xt (B*N,C) bf16
//           K2 per-(b,h): qkv MFMA GEMM + l2norm + MFMA attention -> xa bf16
//           K3 proj MFMA GEMM (48-ch tiles) + output transpose -> (B,C,N) f32
// MFMA 16x16x32 bf16 layouts (verified m89/m91/m120):
//   A: A[m][k] m=lane&15, k=(lane>>4)*8+j ; B: B[k][n] n=lane&15, k=(lane>>4)*8+j
//   D: col=lane&15, row=(lane>>4)*4+r
// Softmax: logits in [-0.178,0.178] -> no max-subtract; clip(1e-6,1) no-op.
// SCALE/ln2 folded into qhat so p = exp2(s).
// R7 changes vs R6 (490us; K2=296 at 43% occ vs R2 242 at 23% occ => NOT
// occupancy-bound; ~26K stall cycles/wave = exposed VMEM latency):
//  (a) K1/xt restored (b128 frag loads, 4x fewer load insts than direct-x f32).
//  (b) Phase A: full-unroll kc loop with EXPLICIT one-ahead register double-buffer
//      (next kc's 8 frag loads issue before current kc's 12 MFMAs).
//  (c) Phase C: 4 S-MFMAs up front (16-wide exp ILP); next kt's K/V LDS reads
//      issued before the exp block. Zero-shuffle PV kept.
//  (d) K3: same one-ahead dbuf, launch_bounds(256,3) so it cannot spill.

#define DIM 384
#define NT 256
#define NH 12
#define HD 32
#define QSCALE (0.17677669529663687f * 1.4426950408889634f)  // SCALE/ln2

typedef __bf16 bf16;
typedef __bf16 bf16x4 __attribute__((ext_vector_type(4)));
typedef __bf16 bf16x8 __attribute__((ext_vector_type(8)));
typedef float f32x4 __attribute__((ext_vector_type(4)));
typedef int i32x2 __attribute__((ext_vector_type(2)));
typedef int i32x4 __attribute__((ext_vector_type(4)));

#define MFMA16(a, b, c) __builtin_amdgcn_mfma_f32_16x16x32_bf16(a, b, c, 0, 0, 0)

// zero-VALU: combine two bf16x4 (2 VGPRs each) into a bf16x8 by register renaming
static __device__ __forceinline__ bf16x8 pack2(bf16x4 lo, bf16x4 hi) {
    i32x2 a = __builtin_bit_cast(i32x2, lo);
    i32x2 c = __builtin_bit_cast(i32x2, hi);
    i32x4 v = {a[0], a[1], c[0], c[1]};
    return __builtin_bit_cast(bf16x8, v);
}

// ---------------- K0: cast weights to bf16 ----------------
__global__ void k_cast_w(const float* __restrict__ qkv_w, const float* __restrict__ proj_w,
                         bf16* __restrict__ wq, bf16* __restrict__ wp) {
    int i = blockIdx.x * 256 + threadIdx.x;
    if (i < 3 * DIM * DIM) wq[i] = (bf16)qkv_w[i];
    if (i < DIM * DIM)     wp[i] = (bf16)proj_w[i];
}

// ---------------- K1: x (B,C,N) f32 -> xt (B*N, C) bf16 ----------------
__global__ void k_transpose_cast(const float* __restrict__ x, bf16* __restrict__ xt) {
    __shared__ float tile[32][33];
    int b = blockIdx.z;
    int c0 = blockIdx.y * 32;
    int n0 = blockIdx.x * 32;
    int tx = threadIdx.x, ty = threadIdx.y;
    const float* xp = x + (size_t)b * DIM * NT;
#pragma unroll
    for (int i = 0; i < 4; ++i) {
        int c = c0 + ty + i * 8;
        tile[ty + i * 8][tx] = xp[(size_t)c * NT + n0 + tx];
    }
    __syncthreads();
    bf16* op = xt + (size_t)b * NT * DIM;
#pragma unroll
    for (int i = 0; i < 4; ++i) {
        int n = n0 + ty + i * 8;
        op[(size_t)n * DIM + c0 + tx] = (bf16)tile[tx][ty + i * 8];
    }
}

// ---------------- K2: fused qkv GEMM + l2norm + attention, one block per (b,h) ----------------
__launch_bounds__(512, 4)
__global__ void k_qkv_attn(const bf16* __restrict__ xt, const bf16* __restrict__ wq,
                           const float* __restrict__ qkv_b, bf16* __restrict__ attn_out) {
    // LDS: kn 20480 + vT 16896 + qn 16384 + bias 384 = 54144 B -> 2 blocks/CU (512thr)
    __shared__ bf16 kn[NT][40];       // normalized k, row pad 40 (80B)
    __shared__ bf16 vT[HD][264];      // v transposed [d][token], pad 264 (528B)
    __shared__ bf16 qn[NT][32];       // normalized q*QSCALE
    __shared__ float bias_s[96];

    // XCD-pinned decode: all 12 head-blocks of a batch share one XCD/L2.
    const int n_ = blockIdx.x;            // grid = 3072 (bijective remap of (h,b))
    const int xcd = n_ & 7;
    const int ww = n_ >> 3;               // 0..383
    const int b = xcd * 32 + ww / 12;
    const int h = ww % 12;

    const int tid = threadIdx.x;
    const int lane = tid & 63, w = tid >> 6;   // w = 0..7
    const int l15 = lane & 15, quad = lane >> 4;

    if (tid < 96) {
        int which = tid >> 5;
        bias_s[tid] = qkv_b[which * DIM + h * HD + (tid & 31)];
    }
    __syncthreads();

    // ---- Phase A: qkv GEMM, wave w owns tokens [w*32, w*32+32), acc[6][2]=48 regs.
    // Explicit one-ahead register dbuf: next kc's 8 b128 loads issue BEFORE current
    // kc's 12 MFMAs (guaranteed ~8 loads in flight per wave).
    f32x4 acc[6][2];
#pragma unroll
    for (int jt = 0; jt < 6; ++jt)
#pragma unroll
        for (int tt = 0; tt < 2; ++tt) acc[jt][tt] = (f32x4){0.f, 0.f, 0.f, 0.f};

    const bf16* xrow[2];
#pragma unroll
    for (int tt = 0; tt < 2; ++tt) {
        int tok = w * 32 + tt * 16 + l15;
        xrow[tt] = xt + (size_t)(b * NT + tok) * DIM + quad * 8;
    }
    const bf16* wrow[6];
#pragma unroll
    for (int jt = 0; jt < 6; ++jt) {
        int jj = jt * 16 + l15;
        int which = jj >> 5;
        wrow[jt] = wq + (size_t)(which * DIM + h * HD + (jj & 31)) * DIM + quad * 8;
    }

    bf16x8 bx[2][2], aw[2][6];
#pragma unroll
    for (int tt = 0; tt < 2; ++tt) bx[0][tt] = *(const bf16x8*)(xrow[tt]);
#pragma unroll
    for (int jt = 0; jt < 6; ++jt) aw[0][jt] = *(const bf16x8*)(wrow[jt]);

#pragma unroll
    for (int kc = 0; kc < 12; ++kc) {
        const int cur = kc & 1, nxt = cur ^ 1;
        if (kc < 11) {
            int k0 = (kc + 1) * 32;
#pragma unroll
            for (int tt = 0; tt < 2; ++tt) bx[nxt][tt] = *(const bf16x8*)(xrow[tt] + k0);
#pragma unroll
            for (int jt = 0; jt < 6; ++jt) aw[nxt][jt] = *(const bf16x8*)(wrow[jt] + k0);
        }
#pragma unroll
        for (int jt = 0; jt < 6; ++jt)
#pragma unroll
            for (int tt = 0; tt < 2; ++tt)
                acc[jt][tt] = MFMA16(aw[cur][jt], bx[cur][tt], acc[jt][tt]);
    }

    // ---- epilogue: +bias, l2-normalize q,k; q->qn, k->kn (b64 stores), v->vT.
#pragma unroll
    for (int tt = 0; tt < 2; ++tt) {
        int tok = w * 32 + tt * 16 + l15;  // = D col for this frag
        float sq = 0.f, sk = 0.f;
#pragma unroll
        for (int jt = 0; jt < 6; ++jt)
#pragma unroll
            for (int r = 0; r < 4; ++r) {
                int j = jt * 16 + quad * 4 + r;  // D row
                float t = acc[jt][tt][r] + bias_s[j];
                acc[jt][tt][r] = t;
                if (jt < 2) sq += t * t;
                else if (jt < 4) sk += t * t;
            }
        sq += __shfl_xor(sq, 16); sq += __shfl_xor(sq, 32);
        sk += __shfl_xor(sk, 16); sk += __shfl_xor(sk, 32);
        float iq = QSCALE / fmaxf(sqrtf(sq), 1e-12f);
        float ik = 1.f / fmaxf(sqrtf(sk), 1e-12f);

        bf16x4 q0v, q1v, k0v, k1v;
#pragma unroll
        for (int r = 0; r < 4; ++r) {
            q0v[r] = (bf16)(acc[0][tt][r] * iq);
            q1v[r] = (bf16)(acc[1][tt][r] * iq);
            k0v[r] = (bf16)(acc[2][tt][r] * ik);
            k1v[r] = (bf16)(acc[3][tt][r] * ik);
        }
        *(bf16x4*)&qn[tok][quad * 4]      = q0v;
        *(bf16x4*)&qn[tok][16 + quad * 4] = q1v;
        *(bf16x4*)&kn[tok][quad * 4]      = k0v;
        *(bf16x4*)&kn[tok][16 + quad * 4] = k1v;
#pragma unroll
        for (int r = 0; r < 4; ++r) {
            vT[quad * 4 + r][tok]      = (bf16)acc[4][tt][r];
            vT[16 + quad * 4 + r][tok] = (bf16)acc[5][tt][r];
        }
    }
    __syncthreads();

    // ---- Phase C: attention, kt-outer, P fully in registers (zero-shuffle PV).
    // k-slot permutation: slot 8q+j <-> token nk0+4q+j (j<4), nk0+16+4q+(j-4) (j>=4);
    // applied identically to pa and vb so the PV product is unchanged.
    bf16x8 qa[2];
#pragma unroll
    for (int qt = 0; qt < 2; ++qt)
        qa[qt] = *(const bf16x8*)&qn[w * 32 + qt * 16 + l15][quad * 8];

    const f32x4 zf = {0.f, 0.f, 0.f, 0.f};
    f32x4 o[2][2];
#pragma unroll
    for (int qt = 0; qt < 2; ++qt) { o[qt][0] = zf; o[qt][1] = zf; }
    float dsm[2] = {0.f, 0.f};

    // preload kt=0 K/V frags
    bf16x8 kb0 = *(const bf16x8*)&kn[l15][quad * 8];
    bf16x8 kb1 = *(const bf16x8*)&kn[16 + l15][quad * 8];
    bf16x4 vp0 = *(const bf16x4*)&vT[l15][quad * 4];
    bf16x4 vp1 = *(const bf16x4*)&vT[l15][16 + quad * 4];
    bf16x4 vp2 = *(const bf16x4*)&vT[16 + l15][quad * 4];
    bf16x4 vp3 = *(const bf16x4*)&vT[16 + l15][16 + quad * 4];

#pragma unroll
    for (int kt = 0; kt < 8; ++kt) {  // 32 keys per chunk
        // all 4 S-MFMAs up front -> 16 independent exps below
        f32x4 s00 = MFMA16(kb0, qa[0], zf);
        f32x4 s01 = MFMA16(kb1, qa[0], zf);
        f32x4 s10 = MFMA16(kb0, qa[1], zf);
        f32x4 s11 = MFMA16(kb1, qa[1], zf);
        bf16x8 vb0 = pack2(vp0, vp1);
        bf16x8 vb1 = pack2(vp2, vp3);
        if (kt < 7) {  // next kt's K/V LDS reads, issued before the exp block
            int nk = kt * 32 + 32;
            kb0 = *(const bf16x8*)&kn[nk + l15][quad * 8];
            kb1 = *(const bf16x8*)&kn[nk + 16 + l15][quad * 8];
            vp0 = *(const bf16x4*)&vT[l15][nk + quad * 4];
            vp1 = *(const bf16x4*)&vT[l15][nk + 16 + quad * 4];
            vp2 = *(const bf16x4*)&vT[16 + l15][nk + quad * 4];
            vp3 = *(const bf16x4*)&vT[16 + l15][nk + 16 + quad * 4];
        }
        bf16x8 pa0, pa1;
        float d0 = 0.f, d1 = 0.f;
#pragma unroll
        for (int r = 0; r < 4; ++r) {
            float p00 = __builtin_amdgcn_exp2f(s00[r]);
            float p01 = __builtin_amdgcn_exp2f(s01[r]);
            float p10 = __builtin_amdgcn_exp2f(s10[r]);
            float p11 = __builtin_amdgcn_exp2f(s11[r]);
            d0 += p00 + p01;  d1 += p10 + p11;
            pa0[r] = (bf16)p00; pa0[4 + r] = (bf16)p01;  // pairs -> v_cvt_pk_bf16_f32
            pa1[r] = (bf16)p10; pa1[4 + r] = (bf16)p11;
        }
        dsm[0] += d0;  dsm[1] += d1;
        o[0][0] = MFMA16(pa0, vb0, o[0][0]);
        o[0][1] = MFMA16(pa0, vb1, o[0][1]);
        o[1][0] = MFMA16(pa1, vb0, o[1][0]);
        o[1][1] = MFMA16(pa1, vb1, o[1][1]);
    }

    // denom: reduce per-lane partials over the 4 quads -> full denom per query
#pragma unroll
    for (int qt = 0; qt < 2; ++qt) {
        dsm[qt] += __shfl_xor(dsm[qt], 16);
        dsm[qt] += __shfl_xor(dsm[qt], 32);
    }
    bf16* opbase = attn_out + (size_t)(b * NT + w * 32) * DIM + h * HD;
#pragma unroll
    for (int qt = 0; qt < 2; ++qt)
#pragma unroll
        for (int r = 0; r < 4; ++r) {
            // O row = query quad*4+r; its denom lives at lane l15 == quad*4+r
            float inv = 1.f / __shfl(dsm[qt], quad * 4 + r);
            int nq = qt * 16 + quad * 4 + r;
            opbase[(size_t)nq * DIM + l15]      = (bf16)(o[qt][0][r] * inv);
            opbase[(size_t)nq * DIM + 16 + l15] = (bf16)(o[qt][1][r] * inv);
        }
}

// ---------------- K3: proj GEMM (48-ch tiles) + output transpose ----------------
__launch_bounds__(256, 3)
__global__ void k_proj(const bf16* __restrict__ xa, const bf16* __restrict__ wp,
                       const float* __restrict__ proj_b, float* __restrict__ out) {
    __shared__ float bias_s[48];
    // XCD-pinned decode (grid = 2048): 8 cb-slices of a batch share one L2.
    const int n_ = blockIdx.x;
    const int xcd = n_ & 7;
    const int ww = n_ >> 3;               // 0..255
    const int b  = xcd * 32 + (ww >> 3);
    const int cb = ww & 7;                // 48-wide slice of 384 out channels

    const int tid = threadIdx.x;
    const int lane = tid & 63, w = tid >> 6;
    const int l15 = lane & 15, quad = lane >> 4;
    if (tid < 48) bias_s[tid] = proj_b[cb * 48 + tid];
    __syncthreads();

    f32x4 acc[3][4];
#pragma unroll
    for (int jt = 0; jt < 3; ++jt)
#pragma unroll
        for (int tt = 0; tt < 4; ++tt) acc[jt][tt] = (f32x4){0.f, 0.f, 0.f, 0.f};

    const bf16* arow[3];
#pragma unroll
    for (int jt = 0; jt < 3; ++jt)
        arow[jt] = wp + (size_t)(cb * 48 + jt * 16 + l15) * DIM + quad * 8;
    const bf16* brow[4];
#pragma unroll
    for (int tt = 0; tt < 4; ++tt)
        brow[tt] = xa + (size_t)(b * NT + w * 64 + tt * 16 + l15) * DIM + quad * 8;

    // explicit one-ahead register dbuf (same scheme as K2 phase A)
    bf16x8 bfr[2][4], afr[2][3];
#pragma unroll
    for (int tt = 0; tt < 4; ++tt) bfr[0][tt] = *(const bf16x8*)(brow[tt]);
#pragma unroll
    for (int jt = 0; jt < 3; ++jt) afr[0][jt] = *(const bf16x8*)(arow[jt]);

#pragma unroll
    for (int kc = 0; kc < 12; ++kc) {
        const int cur = kc & 1, nxt = cur ^ 1;
        if (kc < 11) {
            int k0 = (kc + 1) * 32;
#pragma unroll
            for (int tt = 0; tt < 4; ++tt) bfr[nxt][tt] = *(const bf16x8*)(brow[tt] + k0);
#pragma unroll
            for (int jt = 0; jt < 3; ++jt) afr[nxt][jt] = *(const bf16x8*)(arow[jt] + k0);
        }
#pragma unroll
        for (int jt = 0; jt < 3; ++jt)
#pragma unroll
            for (int tt = 0; tt < 4; ++tt)
                acc[jt][tt] = MFMA16(afr[cur][jt], bfr[cur][tt], acc[jt][tt]);
    }

    float* op = out + (size_t)b * DIM * NT;  // out[b][c][n]
#pragma unroll
    for (int jt = 0; jt < 3; ++jt)
#pragma unroll
        for (int tt = 0; tt < 4; ++tt)
#pragma unroll
            for (int r = 0; r < 4; ++r) {
                int cl = jt * 16 + quad * 4 + r;          // D row = out channel (local)
                int n  = w * 64 + tt * 16 + l15;          // D col = token
                op[(size_t)(cb * 48 + cl) * NT + n] = acc[jt][tt][r] + bias_s[cl];
            }
}

extern "C" void kernel_launch(void* const* d_in, const int* in_sizes, int n_in,
                              void* d_out, int out_size, void* d_ws, size_t ws_size,
                              hipStream_t stream) {
    const float* x      = (const float*)d_in[0];
    const float* qkv_w  = (const float*)d_in[1];
    const float* qkv_b  = (const float*)d_in[2];
    const float* proj_w = (const float*)d_in[3];
    const float* proj_b = (const float*)d_in[4];
    float* out = (float*)d_out;

    char* ws = (char*)d_ws;
    bf16* xt = (bf16*)ws;                    // 256*256*384*2 = 50,331,648 B
    bf16* xa = (bf16*)(ws + 50331648);       // 50,331,648 B
    bf16* wq = (bf16*)(ws + 100663296);      // 884,736 B
    bf16* wp = (bf16*)(ws + 101548032);      // 294,912 B  (total 101,842,944 B)

    k_cast_w<<<dim3(1728), dim3(256), 0, stream>>>(qkv_w, proj_w, wq, wp);
    k_transpose_cast<<<dim3(8, 12, 256), dim3(32, 8), 0, stream>>>(x, xt);
    k_qkv_attn<<<dim3(NH * 256), dim3(512), 0, stream>>>(xt, wq, qkv_b, xa);
    k_proj<<<dim3(8 * 256), dim3(256), 0, stream>>>(xa, wp, proj_b, out);
}

// Round 8
// 367.720 us; speedup vs baseline: 1.5583x; 1.5583x over previous
//
#include <hip/hip_runtime.h>

// WindowAttention: B=256 windows, N=256 tokens, C=384, 12 heads, d=32.
// Pipeline: K0 cast weights->bf16 | K1 transpose-cast x -> xt (B*N,C) bf16
//           K2 per-(b,h): qkv MFMA GEMM + l2norm + MFMA attention -> xa bf16
//           K3 proj MFMA GEMM (48-ch tiles) + output transpose -> (B,C,N) f32
// MFMA 16x16x32 bf16 layouts (verified m89/m91/m120):
//   A: A[m][k] m=lane&15, k=(lane>>4)*8+j ; B: B[k][n] n=lane&15, k=(lane>>4)*8+j
//   D: col=lane&15, row=(lane>>4)*4+r
// Softmax: logits in [-0.178,0.178] -> no max-subtract; clip(1e-6,1) no-op.
// SCALE/ln2 folded into qhat so p = exp2(s).
// R8 changes vs R7 (573us, invalid: (512,4) reg budget -> 380MB spill traffic) and
// vs the clean R2/R6 evidence (perf tracks phase-A global-loads-per-MFMA; weight
// frag loads are 16-segment L2 gathers, 73.7KB/head re-swept per wave, L1 thrash):
//  (a) WEIGHTS STAGED IN LDS once per block (coalesced reg-staging, 9 b128/thread);
//      phase A A-frags via ds_read_b128 from LDS. Row stride 400 elems (800B).
//  (b) LDS UNION: weight buffer (76.8KB) overlaid by phase-C kn/vT/qn (53.8KB);
//      barrier between last weight read and epilogue writes. 77.2KB total.
//  (c) Reg safety: launch_bounds(512,3) / (256,3) -- generous budgets, NO spills
//      (R3/R7 lesson: spills cost more than any occupancy gain).
//  (d) K3: same staging for its 48x384 wp tile (38.4KB), one-ahead dbuf on xa.

#define DIM 384
#define NT 256
#define NH 12
#define HD 32
#define QSCALE (0.17677669529663687f * 1.4426950408889634f)  // SCALE/ln2

typedef __bf16 bf16;
typedef __bf16 bf16x4 __attribute__((ext_vector_type(4)));
typedef __bf16 bf16x8 __attribute__((ext_vector_type(8)));
typedef float f32x4 __attribute__((ext_vector_type(4)));
typedef int i32x2 __attribute__((ext_vector_type(2)));
typedef int i32x4 __attribute__((ext_vector_type(4)));

#define MFMA16(a, b, c) __builtin_amdgcn_mfma_f32_16x16x32_bf16(a, b, c, 0, 0, 0)

// zero-VALU: combine two bf16x4 (2 VGPRs each) into a bf16x8 by register renaming
static __device__ __forceinline__ bf16x8 pack2(bf16x4 lo, bf16x4 hi) {
    i32x2 a = __builtin_bit_cast(i32x2, lo);
    i32x2 c = __builtin_bit_cast(i32x2, hi);
    i32x4 v = {a[0], a[1], c[0], c[1]};
    return __builtin_bit_cast(bf16x8, v);
}

// ---------------- K0: cast weights to bf16 ----------------
__global__ void k_cast_w(const float* __restrict__ qkv_w, const float* __restrict__ proj_w,
                         bf16* __restrict__ wq, bf16* __restrict__ wp) {
    int i = blockIdx.x * 256 + threadIdx.x;
    if (i < 3 * DIM * DIM) wq[i] = (bf16)qkv_w[i];
    if (i < DIM * DIM)     wp[i] = (bf16)proj_w[i];
}

// ---------------- K1: x (B,C,N) f32 -> xt (B*N, C) bf16 ----------------
__global__ void k_transpose_cast(const float* __restrict__ x, bf16* __restrict__ xt) {
    __shared__ float tile[32][33];
    int b = blockIdx.z;
    int c0 = blockIdx.y * 32;
    int n0 = blockIdx.x * 32;
    int tx = threadIdx.x, ty = threadIdx.y;
    const float* xp = x + (size_t)b * DIM * NT;
#pragma unroll
    for (int i = 0; i < 4; ++i) {
        int c = c0 + ty + i * 8;
        tile[ty + i * 8][tx] = xp[(size_t)c * NT + n0 + tx];
    }
    __syncthreads();
    bf16* op = xt + (size_t)b * NT * DIM;
#pragma unroll
    for (int i = 0; i < 4; ++i) {
        int n = n0 + ty + i * 8;
        op[(size_t)n * DIM + c0 + tx] = (bf16)tile[tx][ty + i * 8];
    }
}

// ---------------- K2: fused qkv GEMM + l2norm + attention, one block per (b,h) ----------------
__launch_bounds__(512, 3)
__global__ void k_qkv_attn(const bf16* __restrict__ xt, const bf16* __restrict__ wq,
                           const float* __restrict__ qkv_b, bf16* __restrict__ attn_out) {
    // LDS union: phase A = staged weights 96x400 bf16 (76,800B);
    //            phase C = kn 20,480 + vT 16,896 + qn 16,384 = 53,760B (overlaid).
    __shared__ __align__(16) char smem[76800];
    bf16 (*wsm)[400] = (bf16(*)[400])smem;              // 96 rows of per-head W
    bf16 (*kn)[40]   = (bf16(*)[40])smem;               // normalized k (pad 40)
    bf16 (*vT)[264]  = (bf16(*)[264])(smem + 20480);    // v^T [d][token] (pad 264)
    bf16 (*qn)[32]   = (bf16(*)[32])(smem + 37376);     // normalized q*QSCALE
    __shared__ float bias_s[96];

    // XCD-pinned decode: all 12 head-blocks of a batch share one XCD/L2.
    const int n_ = blockIdx.x;            // grid = 3072 (bijective remap of (h,b))
    const int xcd = n_ & 7;
    const int ww = n_ >> 3;               // 0..383
    const int b = xcd * 32 + ww / 12;
    const int h = ww % 12;

    const int tid = threadIdx.x;
    const int lane = tid & 63, w = tid >> 6;   // w = 0..7
    const int l15 = lane & 15, quad = lane >> 4;

    if (tid < 96) {
        int which = tid >> 5;
        bias_s[tid] = qkv_b[which * DIM + h * HD + (tid & 31)];
    }
    // ---- stage this head's 96x384 weight tile into LDS (coalesced b128 pairs) ----
    // chunk c (of 4608): row c/48, 16B-chunk c%48. 9 chunks per thread.
#pragma unroll
    for (int i = 0; i < 9; ++i) {
        int c = tid + i * 512;
        int row = c / 48, ch = c % 48;
        int grow = (row >> 5) * DIM + h * HD + (row & 31);   // q/k/v row in wq
        *(bf16x8*)&wsm[row][ch * 8] = *(const bf16x8*)(wq + (size_t)grow * DIM + ch * 8);
    }
    __syncthreads();

    // ---- Phase A: qkv GEMM, wave w owns tokens [w*32, w*32+32), acc[6][2]=48 regs.
    // A-frags from LDS (ds_read_b128); x B-frags global with one-ahead dbuf.
    f32x4 acc[6][2];
#pragma unroll
    for (int jt = 0; jt < 6; ++jt)
#pragma unroll
        for (int tt = 0; tt < 2; ++tt) acc[jt][tt] = (f32x4){0.f, 0.f, 0.f, 0.f};

    const bf16* xrow[2];
#pragma unroll
    for (int tt = 0; tt < 2; ++tt) {
        int tok = w * 32 + tt * 16 + l15;
        xrow[tt] = xt + (size_t)(b * NT + tok) * DIM + quad * 8;
    }

    bf16x8 bx[2][2];
#pragma unroll
    for (int tt = 0; tt < 2; ++tt) bx[0][tt] = *(const bf16x8*)(xrow[tt]);

#pragma unroll
    for (int kc = 0; kc < 12; ++kc) {
        const int cur = kc & 1, nxt = cur ^ 1;
        if (kc < 11) {
            int k0 = (kc + 1) * 32;
#pragma unroll
            for (int tt = 0; tt < 2; ++tt) bx[nxt][tt] = *(const bf16x8*)(xrow[tt] + k0);
        }
        bf16x8 aw[6];
#pragma unroll
        for (int jt = 0; jt < 6; ++jt)
            aw[jt] = *(const bf16x8*)&wsm[jt * 16 + l15][kc * 32 + quad * 8];
#pragma unroll
        for (int jt = 0; jt < 6; ++jt)
#pragma unroll
            for (int tt = 0; tt < 2; ++tt)
                acc[jt][tt] = MFMA16(aw[jt], bx[cur][tt], acc[jt][tt]);
    }
    __syncthreads();   // weights dead; epilogue overlays kn/qn/vT onto wsm

    // ---- epilogue: +bias, l2-normalize q,k; q->qn, k->kn (b64 stores), v->vT.
#pragma unroll
    for (int tt = 0; tt < 2; ++tt) {
        int tok = w * 32 + tt * 16 + l15;  // = D col for this frag
        float sq = 0.f, sk = 0.f;
#pragma unroll
        for (int jt = 0; jt < 6; ++jt)
#pragma unroll
            for (int r = 0; r < 4; ++r) {
                int j = jt * 16 + quad * 4 + r;  // D row
                float t = acc[jt][tt][r] + bias_s[j];
                acc[jt][tt][r] = t;
                if (jt < 2) sq += t * t;
                else if (jt < 4) sk += t * t;
            }
        sq += __shfl_xor(sq, 16); sq += __shfl_xor(sq, 32);
        sk += __shfl_xor(sk, 16); sk += __shfl_xor(sk, 32);
        float iq = QSCALE / fmaxf(sqrtf(sq), 1e-12f);
        float ik = 1.f / fmaxf(sqrtf(sk), 1e-12f);

        bf16x4 q0v, q1v, k0v, k1v;
#pragma unroll
        for (int r = 0; r < 4; ++r) {
            q0v[r] = (bf16)(acc[0][tt][r] * iq);
            q1v[r] = (bf16)(acc[1][tt][r] * iq);
            k0v[r] = (bf16)(acc[2][tt][r] * ik);
            k1v[r] = (bf16)(acc[3][tt][r] * ik);
        }
        *(bf16x4*)&qn[tok][quad * 4]      = q0v;
        *(bf16x4*)&qn[tok][16 + quad * 4] = q1v;
        *(bf16x4*)&kn[tok][quad * 4]      = k0v;
        *(bf16x4*)&kn[tok][16 + quad * 4] = k1v;
#pragma unroll
        for (int r = 0; r < 4; ++r) {
            vT[quad * 4 + r][tok]      = (bf16)acc[4][tt][r];
            vT[16 + quad * 4 + r][tok] = (bf16)acc[5][tt][r];
        }
    }
    __syncthreads();

    // ---- Phase C: attention, kt-outer, P fully in registers (zero-shuffle PV).
    // k-slot permutation: slot 8q+j <-> token nk0+4q+j (j<4), nk0+16+4q+(j-4) (j>=4);
    // applied identically to pa and vb so the PV product is unchanged.
    bf16x8 qa[2];
#pragma unroll
    for (int qt = 0; qt < 2; ++qt)
        qa[qt] = *(const bf16x8*)&qn[w * 32 + qt * 16 + l15][quad * 8];

    const f32x4 zf = {0.f, 0.f, 0.f, 0.f};
    f32x4 o[2][2];
#pragma unroll
    for (int qt = 0; qt < 2; ++qt) { o[qt][0] = zf; o[qt][1] = zf; }
    float dsm[2] = {0.f, 0.f};

    // preload kt=0 K/V frags
    bf16x8 kb0 = *(const bf16x8*)&kn[l15][quad * 8];
    bf16x8 kb1 = *(const bf16x8*)&kn[16 + l15][quad * 8];
    bf16x4 vp0 = *(const bf16x4*)&vT[l15][quad * 4];
    bf16x4 vp1 = *(const bf16x4*)&vT[l15][16 + quad * 4];
    bf16x4 vp2 = *(const bf16x4*)&vT[16 + l15][quad * 4];
    bf16x4 vp3 = *(const bf16x4*)&vT[16 + l15][16 + quad * 4];

#pragma unroll
    for (int kt = 0; kt < 8; ++kt) {  // 32 keys per chunk
        // all 4 S-MFMAs up front -> 16 independent exps below
        f32x4 s00 = MFMA16(kb0, qa[0], zf);
        f32x4 s01 = MFMA16(kb1, qa[0], zf);
        f32x4 s10 = MFMA16(kb0, qa[1], zf);
        f32x4 s11 = MFMA16(kb1, qa[1], zf);
        bf16x8 vb0 = pack2(vp0, vp1);
        bf16x8 vb1 = pack2(vp2, vp3);
        if (kt < 7) {  // next kt's K/V LDS reads, issued before the exp block
            int nk = kt * 32 + 32;
            kb0 = *(const bf16x8*)&kn[nk + l15][quad * 8];
            kb1 = *(const bf16x8*)&kn[nk + 16 + l15][quad * 8];
            vp0 = *(const bf16x4*)&vT[l15][nk + quad * 4];
            vp1 = *(const bf16x4*)&vT[l15][nk + 16 + quad * 4];
            vp2 = *(const bf16x4*)&vT[16 + l15][nk + quad * 4];
            vp3 = *(const bf16x4*)&vT[16 + l15][nk + 16 + quad * 4];
        }
        bf16x8 pa0, pa1;
        float d0 = 0.f, d1 = 0.f;
#pragma unroll
        for (int r = 0; r < 4; ++r) {
            float p00 = __builtin_amdgcn_exp2f(s00[r]);
            float p01 = __builtin_amdgcn_exp2f(s01[r]);
            float p10 = __builtin_amdgcn_exp2f(s10[r]);
            float p11 = __builtin_amdgcn_exp2f(s11[r]);
            d0 += p00 + p01;  d1 += p10 + p11;
            pa0[r] = (bf16)p00; pa0[4 + r] = (bf16)p01;  // pairs -> v_cvt_pk_bf16_f32
            pa1[r] = (bf16)p10; pa1[4 + r] = (bf16)p11;
        }
        dsm[0] += d0;  dsm[1] += d1;
        o[0][0] = MFMA16(pa0, vb0, o[0][0]);
        o[0][1] = MFMA16(pa0, vb1, o[0][1]);
        o[1][0] = MFMA16(pa1, vb0, o[1][0]);
        o[1][1] = MFMA16(pa1, vb1, o[1][1]);
    }

    // denom: reduce per-lane partials over the 4 quads -> full denom per query
#pragma unroll
    for (int qt = 0; qt < 2; ++qt) {
        dsm[qt] += __shfl_xor(dsm[qt], 16);
        dsm[qt] += __shfl_xor(dsm[qt], 32);
    }
    bf16* opbase = attn_out + (size_t)(b * NT + w * 32) * DIM + h * HD;
#pragma unroll
    for (int qt = 0; qt < 2; ++qt)
#pragma unroll
        for (int r = 0; r < 4; ++r) {
            // O row = query quad*4+r; its denom lives at lane l15 == quad*4+r
            float inv = 1.f / __shfl(dsm[qt], quad * 4 + r);
            int nq = qt * 16 + quad * 4 + r;
            opbase[(size_t)nq * DIM + l15]      = (bf16)(o[qt][0][r] * inv);
            opbase[(size_t)nq * DIM + 16 + l15] = (bf16)(o[qt][1][r] * inv);
        }
}

// ---------------- K3: proj GEMM (48-ch tiles, LDS-staged weights) ----------------
__launch_bounds__(256, 3)
__global__ void k_proj(const bf16* __restrict__ xa, const bf16* __restrict__ wp,
                       const float* __restrict__ proj_b, float* __restrict__ out) {
    __shared__ __align__(16) bf16 wsm[48][400];   // 38,400B staged weight tile
    __shared__ float bias_s[48];
    // XCD-pinned decode (grid = 2048): 8 cb-slices of a batch share one L2.
    const int n_ = blockIdx.x;
    const int xcd = n_ & 7;
    const int ww = n_ >> 3;               // 0..255
    const int b  = xcd * 32 + (ww >> 3);
    const int cb = ww & 7;                // 48-wide slice of 384 out channels

    const int tid = threadIdx.x;
    const int lane = tid & 63, w = tid >> 6;
    const int l15 = lane & 15, quad = lane >> 4;
    if (tid < 48) bias_s[tid] = proj_b[cb * 48 + tid];
    // stage 48x384 wp tile (2304 chunks, 9 per thread)
#pragma unroll
    for (int i = 0; i < 9; ++i) {
        int c = tid + i * 256;
        int row = c / 48, ch = c % 48;
        *(bf16x8*)&wsm[row][ch * 8] =
            *(const bf16x8*)(wp + (size_t)(cb * 48 + row) * DIM + ch * 8);
    }
    __syncthreads();

    f32x4 acc[3][4];
#pragma unroll
    for (int jt = 0; jt < 3; ++jt)
#pragma unroll
        for (int tt = 0; tt < 4; ++tt) acc[jt][tt] = (f32x4){0.f, 0.f, 0.f, 0.f};

    const bf16* brow[4];
#pragma unroll
    for (int tt = 0; tt < 4; ++tt)
        brow[tt] = xa + (size_t)(b * NT + w * 64 + tt * 16 + l15) * DIM + quad * 8;

    // one-ahead dbuf on xa B-frags; A-frags from LDS per kc
    bf16x8 bfr[2][4];
#pragma unroll
    for (int tt = 0; tt < 4; ++tt) bfr[0][tt] = *(const bf16x8*)(brow[tt]);

#pragma unroll
    for (int kc = 0; kc < 12; ++kc) {
        const int cur = kc & 1, nxt = cur ^ 1;
        if (kc < 11) {
            int k0 = (kc + 1) * 32;
#pragma unroll
            for (int tt = 0; tt < 4; ++tt) bfr[nxt][tt] = *(const bf16x8*)(brow[tt] + k0);
        }
        bf16x8 afr[3];
#pragma unroll
        for (int jt = 0; jt < 3; ++jt)
            afr[jt] = *(const bf16x8*)&wsm[jt * 16 + l15][kc * 32 + quad * 8];
#pragma unroll
        for (int jt = 0; jt < 3; ++jt)
#pragma unroll
            for (int tt = 0; tt < 4; ++tt)
                acc[jt][tt] = MFMA16(afr[jt], bfr[cur][tt], acc[jt][tt]);
    }

    float* op = out + (size_t)b * DIM * NT;  // out[b][c][n]
#pragma unroll
    for (int jt = 0; jt < 3; ++jt)
#pragma unroll
        for (int tt = 0; tt < 4; ++tt)
#pragma unroll
            for (int r = 0; r < 4; ++r) {
                int cl = jt * 16 + quad * 4 + r;          // D row = out channel (local)
                int n  = w * 64 + tt * 16 + l15;          // D col = token
                op[(size_t)(cb * 48 + cl) * NT + n] = acc[jt][tt][r] + bias_s[cl];
            }
}

extern "C" void kernel_launch(void* const* d_in, const int* in_sizes, int n_in,
                              void* d_out, int out_size, void* d_ws, size_t ws_size,
                              hipStream_t stream) {
    const float* x      = (const float*)d_in[0];
    const float* qkv_w  = (const float*)d_in[1];
    const float* qkv_b  = (const float*)d_in[2];
    const float* proj_w = (const float*)d_in[3];
    const float* proj_b = (const float*)d_in[4];
    float* out = (float*)d_out;

    char* ws = (char*)d_ws;
    bf16* xt = (bf16*)ws;                    // 256*256*384*2 = 50,331,648 B
    bf16* xa = (bf16*)(ws + 50331648);       // 50,331,648 B
    bf16* wq = (bf16*)(ws + 100663296);      // 884,736 B
    bf16* wp = (bf16*)(ws + 101548032);      // 294,912 B  (total 101,842,944 B)

    k_cast_w<<<dim3(1728), dim3(256), 0, stream>>>(qkv_w, proj_w, wq, wp);
    k_transpose_cast<<<dim3(8, 12, 256), dim3(32, 8), 0, stream>>>(x, xt);
    k_qkv_attn<<<dim3(NH * 256), dim3(512), 0, stream>>>(xt, wq, qkv_b, xa);
    k_proj<<<dim3(8 * 256), dim3(256), 0, stream>>>(xa, wp, proj_b, out);
}